// Round 2
// baseline (1188.878 us; speedup 1.0000x reference)
//
#include <hip/hip_runtime.h>
#include <stdint.h>

typedef unsigned short u16;
typedef unsigned int u32;
typedef __bf16 bf16x8 __attribute__((ext_vector_type(8)));
typedef float f32x4 __attribute__((ext_vector_type(4)));

#define BM 128
#define BN 128
#define BK 64

__device__ __forceinline__ u16 f2bf(float x) {
  union { float f; uint32_t u; } c; c.f = x;
  uint32_t r = (c.u + 0x7FFFu + ((c.u >> 16) & 1u)) >> 16;
  return (u16)r;
}
__device__ __forceinline__ float bf2f(u16 v) {
  union { uint32_t u; float f; } c; c.u = ((uint32_t)v) << 16;
  return c.f;
}

// async global->LDS, 16B per lane; LDS dest = wave-uniform base + lane*16
__device__ __forceinline__ void async_copy16(const u16* g, u16* l) {
  __builtin_amdgcn_global_load_lds(
      (const __attribute__((address_space(1))) void*)g,
      (__attribute__((address_space(3))) void*)l,
      16, 0, 0);
}

// ---------- dtype detection: bf16 weights never have exp==0xFF patterns ----
__global__ void detect_dtype(const u16* __restrict__ w, int n, u32* __restrict__ flag) {
  __shared__ int cnt;
  if (threadIdx.x == 0) cnt = 0;
  __syncthreads();
  int c = 0;
  for (int i = threadIdx.x; i < n; i += 256)
    if ((w[i] & 0x7F80u) == 0x7F80u) c++;
  atomicAdd(&cnt, c);
  __syncthreads();
  if (threadIdx.x == 0) *flag = (cnt > 32) ? 1u : 0u;  // 1 => inputs are f32
}

// normalize input tensor to bf16 (copy if already bf16, convert if f32)
__global__ void normalize_in(const void* __restrict__ src, u16* __restrict__ dst,
                             const u32* __restrict__ flag) {
  long i = (long)blockIdx.x * 256 + threadIdx.x;
  if (*flag) dst[i] = f2bf(((const float*)src)[i]);
  else       dst[i] = ((const u16*)src)[i];
}

// write bf16 result to d_out in the harness's dtype
__global__ void writeout(const u16* __restrict__ o, void* __restrict__ dout,
                         const u32* __restrict__ flag) {
  long i = (long)blockIdx.x * 256 + threadIdx.x;
  u16 v = o[i];
  if (*flag) ((float*)dout)[i] = bf2f(v);
  else       ((u16*)dout)[i] = v;
}

__global__ void zerofill_u16(u16* __restrict__ p) {
  long i = (long)blockIdx.x * 256 + threadIdx.x;
  p[i] = 0;
}

// ---------- NT GEMM: A [M,K] bf16, B [N,K] bf16, C [M,N] ------------------
// MODE 0: bf16 out (acc*scale). MODE 1: f32 out (acc*scale).
// causal: skip 128-tiles strictly above diagonal. trik: K-loop < m0+BM.
template <int MODE>
__global__ __launch_bounds__(256, 2)
void gemm_nt(const u16* __restrict__ A, const u16* __restrict__ B, void* __restrict__ Cv,
             int K, int lda, int ldb, int ldc,
             long sA, long sB, long sC,
             float scale, int causal, int trik)
{
  const int bm = blockIdx.y, bn = blockIdx.x, bz = blockIdx.z;
  if (causal && bn > bm) return;

  __shared__ u16 As[BM * BK];
  __shared__ u16 Bs[BN * BK];

  A += (long)bz * sA;
  B += (long)bz * sB;

  const int tid  = threadIdx.x;
  const int wid  = tid >> 6;
  const int lane = tid & 63;
  const int l16  = lane & 15;
  const int lk   = lane >> 4;       // 0..3
  const int srow = lane >> 3;       // 0..7   (staging row within 8-row slab)
  const int scol = (lane & 7) * 8;  // staging col (elements)
  const int m0 = bm * BM, n0 = bn * BN;

  int nk = K / BK;
  if (trik) { int lim = (m0 + BM) / BK; if (lim < nk) nk = lim; }

  f32x4 acc[4][4] = {};

  for (int kt = 0; kt < nk; ++kt) {
    const int k0 = kt * BK;
#pragma unroll
    for (int c = 0; c < 4; ++c) {
      const int rb = wid * 32 + c * 8;  // wave-uniform 8-row slab base
      async_copy16(A + (long)(m0 + rb + srow) * lda + (k0 + scol), As + rb * BK);
      async_copy16(B + (long)(n0 + rb + srow) * ldb + (k0 + scol), Bs + rb * BK);
    }
    __syncthreads();
#pragma unroll
    for (int kh = 0; kh < 2; ++kh) {
      bf16x8 av[4], bv[4];
#pragma unroll
      for (int i = 0; i < 4; ++i) {
        av[i] = *(const bf16x8*)(As + ((wid >> 1) * 64 + i * 16 + l16) * BK + kh * 32 + lk * 8);
        bv[i] = *(const bf16x8*)(Bs + ((wid & 1) * 64 + i * 16 + l16) * BK + kh * 32 + lk * 8);
      }
#pragma unroll
      for (int mi = 0; mi < 4; ++mi)
#pragma unroll
        for (int ni = 0; ni < 4; ++ni)
          acc[mi][ni] = __builtin_amdgcn_mfma_f32_16x16x32_bf16(av[mi], bv[ni], acc[mi][ni], 0, 0, 0);
    }
    __syncthreads();
  }

  // C/D layout (m89-verified): col = lane&15, row = (lane>>4)*4 + reg
  const int rb0 = m0 + (wid >> 1) * 64;
  const int cb0 = n0 + (wid & 1) * 64;
  if constexpr (MODE == 0) {
    u16* Cp = (u16*)Cv + (long)bz * sC;
#pragma unroll
    for (int mi = 0; mi < 4; ++mi)
#pragma unroll
      for (int ni = 0; ni < 4; ++ni) {
        const int row = rb0 + mi * 16 + lk * 4;
        const int col = cb0 + ni * 16 + l16;
#pragma unroll
        for (int r = 0; r < 4; ++r)
          Cp[(long)(row + r) * ldc + col] = f2bf(acc[mi][ni][r] * scale);
      }
  } else {
    float* Cp = (float*)Cv + (long)bz * sC;
#pragma unroll
    for (int mi = 0; mi < 4; ++mi)
#pragma unroll
      for (int ni = 0; ni < 4; ++ni) {
        const int row = rb0 + mi * 16 + lk * 4;
        const int col = cb0 + ni * 16 + l16;
#pragma unroll
        for (int r = 0; r < 4; ++r)
          Cp[(long)(row + r) * ldc + col] = acc[mi][ni][r] * scale;
      }
  }
}

// ---------- bf16 [R][C] -> [C][R], 64x64 LDS tiles -------------------------
__global__ __launch_bounds__(256)
void transpose_bf16(const u16* __restrict__ in, u16* __restrict__ out,
                    int R, int C, long sIn, long sOut)
{
  __shared__ u16 tile[64][72];
  const int bz = blockIdx.z;
  in  += (long)bz * sIn;
  out += (long)bz * sOut;
  const int r0 = blockIdx.y * 64, c0 = blockIdx.x * 64;
  const int tid = threadIdx.x;
#pragma unroll
  for (int p = 0; p < 2; ++p) {
    int v = tid + p * 256;
    int row = v >> 3, c8 = (v & 7) * 8;
    union { uint4 q; u16 s[8]; } t;
    t.q = *(const uint4*)(in + (long)(r0 + row) * C + c0 + c8);
#pragma unroll
    for (int i = 0; i < 8; ++i) tile[row][c8 + i] = t.s[i];
  }
  __syncthreads();
#pragma unroll
  for (int p = 0; p < 2; ++p) {
    int v = tid + p * 256;
    int oc = v >> 3, r8 = (v & 7) * 8;
    union { uint4 q; u16 s[8]; } t;
#pragma unroll
    for (int i = 0; i < 8; ++i) t.s[i] = tile[r8 + i][oc];
    *(uint4*)(out + (long)(c0 + oc) * R + r0 + r8) = t.q;
  }
}

// ---------- causal softmax, f32 scores in, bf16 probs IN-PLACE at row head -
// all reads of the f32 row complete before the barrier that precedes writes.
__global__ __launch_bounds__(256)
void softmax_causal(char* __restrict__ base, long rowStrideB, int S, int modS)
{
  const long r = blockIdx.x;
  const int i = (int)(r % modS);
  float* sc = (float*)(base + r * rowStrideB);
  u16*   pr = (u16*)(base + r * rowStrideB);
  const int n = i + 1;
  const int tid = threadIdx.x;
  const int wv = tid >> 6, lane = tid & 63;
  __shared__ float red[4];

  float m = -3.0e38f;
  for (int j = tid; j < n; j += 256) m = fmaxf(m, sc[j]);
#pragma unroll
  for (int o = 32; o > 0; o >>= 1) m = fmaxf(m, __shfl_xor(m, o));
  if (lane == 0) red[wv] = m;
  __syncthreads();
  m = fmaxf(fmaxf(red[0], red[1]), fmaxf(red[2], red[3]));
  __syncthreads();

  float e[8];
  float s = 0.f;
  int cnt = 0;
  for (int j = tid; j < n; j += 256) { float x = __expf(sc[j] - m); e[cnt++] = x; s += x; }
#pragma unroll
  for (int o = 32; o > 0; o >>= 1) s += __shfl_xor(s, o);
  if (lane == 0) red[wv] = s;
  __syncthreads();                      // also: last f32 read was before here
  s = red[0] + red[1] + red[2] + red[3];
  const float inv = 1.0f / s;

  cnt = 0;
  for (int j = tid; j < S; j += 256) {
    u16 v = 0;
    if (j < n) v = f2bf(e[cnt++] * inv);
    pr[j] = v;                          // overwrites first half of f32 row
  }
}

extern "C" void kernel_launch(void* const* d_in, const int* in_sizes, int n_in,
                              void* d_out, int out_size, void* d_ws, size_t ws_size,
                              hipStream_t stream)
{
  (void)in_sizes; (void)n_in; (void)out_size;
  const int Bb = 4, S = 2048, D = 1024;
  const long SD = (long)S * D;            // 2,097,152
  const long SS = (long)S * S;            // 4,194,304
  const long N_X = (long)Bb * SD;         // 8,388,608 elements
  const long N_W = (long)D * D;           // 1,048,576 elements

  char* ws = (char*)d_ws;
  size_t off = 0;
  auto take = [&](size_t bytes) -> void* {
    void* p = ws + off;
    off = (off + bytes + 255) & ~((size_t)255);
    return p;
  };

  // ---- common small allocations
  u32* flag = (u32*)take(4096);
  u16* xn   = (u16*)take((size_t)N_X * 2);      // normalized x, bf16
  u16* wqn  = (u16*)take((size_t)N_W * 2);
  u16* wkn  = (u16*)take((size_t)N_W * 2);
  u16* wvn  = (u16*)take((size_t)N_W * 2);
  u16* WqT  = (u16*)take((size_t)N_W * 2);
  u16* WkT  = (u16*)take((size_t)N_W * 2);
  u16* WvT  = (u16*)take((size_t)N_W * 2);
  const size_t off_common = off;                // ~45.1 MB

  // plan A extra: Q,K,V,VT (4x16MB) + scores f32 (64MB) + Otmp (16MB) = ~181 MB total
  const size_t needA = off_common + (size_t)(4 * SD * 2 * 4) + (size_t)(Bb * SS * 4)
                     + (size_t)(N_X * 2) + 4096;
  // plan C extra: Qb,Kb,Vb,VTb (4x4MB) + scores_b f32 (16MB) + Otmp (16MB) = ~80 MB total
  const size_t needC = off_common + (size_t)(4 * SD * 2) + (size_t)(SS * 4)
                     + (size_t)(N_X * 2) + 4096;

  if (ws_size < needC) {
    // not enough workspace — emit zeros as a distinct diagnostic signature
    zerofill_u16<<<(int)(N_X / 256), 256, 0, stream>>>((u16*)d_out);
    return;
  }

  // ---- dtype detect + normalize (graph-safe: device-side flag) ----
  detect_dtype<<<1, 256, 0, stream>>>((const u16*)d_in[1], (int)N_W, flag);
  normalize_in<<<(int)(N_X / 256), 256, 0, stream>>>(d_in[0], xn, flag);
  normalize_in<<<(int)(N_W / 256), 256, 0, stream>>>(d_in[1], wqn, flag);
  normalize_in<<<(int)(N_W / 256), 256, 0, stream>>>(d_in[2], wkn, flag);
  normalize_in<<<(int)(N_W / 256), 256, 0, stream>>>(d_in[3], wvn, flag);

  // W -> W^T (NT GEMM form)
  transpose_bf16<<<dim3(D / 64, D / 64, 1), 256, 0, stream>>>(wqn, WqT, D, D, 0, 0);
  transpose_bf16<<<dim3(D / 64, D / 64, 1), 256, 0, stream>>>(wkn, WkT, D, D, 0, 0);
  transpose_bf16<<<dim3(D / 64, D / 64, 1), 256, 0, stream>>>(wvn, WvT, D, D, 0, 0);

  const float scl = 0.03125f;  // 1024^-0.5

  if (ws_size >= needA) {
    // ================= plan A: fully batched =================
    u16*   Q    = (u16*)take((size_t)N_X * 2);
    u16*   Kb   = (u16*)take((size_t)N_X * 2);
    u16*   V    = (u16*)take((size_t)N_X * 2);
    u16*   VT   = (u16*)take((size_t)N_X * 2);
    float* sc   = (float*)take((size_t)Bb * SS * 4);
    u16*   Otmp = (u16*)take((size_t)N_X * 2);

    dim3 gq(D / BN, (int)(N_X / D) / BM, 1);   // (8, 64)
    gemm_nt<0><<<gq, 256, 0, stream>>>(xn, WqT, Q,  D, D, D, D, 0, 0, 0, 1.f, 0, 0);
    gemm_nt<0><<<gq, 256, 0, stream>>>(xn, WkT, Kb, D, D, D, D, 0, 0, 0, 1.f, 0, 0);
    gemm_nt<0><<<gq, 256, 0, stream>>>(xn, WvT, V,  D, D, D, D, 0, 0, 0, 1.f, 0, 0);

    transpose_bf16<<<dim3(D / 64, S / 64, Bb), 256, 0, stream>>>(V, VT, S, D, SD, SD);

    gemm_nt<1><<<dim3(S / BN, S / BM, Bb), 256, 0, stream>>>(Q, Kb, sc, D, D, D, S,
                                                             SD, SD, SS, scl, 1, 0);
    softmax_causal<<<Bb * S, 256, 0, stream>>>((char*)sc, (long)S * 4, S, S);
    // probs live in-place: u16 rows of stride 2S at the head of each f32 row
    gemm_nt<0><<<dim3(D / BN, S / BM, Bb), 256, 0, stream>>>((u16*)sc, VT, Otmp,
                                                             S, 2 * S, S, D,
                                                             2 * SS, SD, SD, 1.f, 0, 1);
    writeout<<<(int)(N_X / 256), 256, 0, stream>>>(Otmp, d_out, flag);
  } else {
    // ================= plan C: per-batch (~80 MB) =================
    u16*   Qb   = (u16*)take((size_t)SD * 2);
    u16*   Kbb  = (u16*)take((size_t)SD * 2);
    u16*   Vb   = (u16*)take((size_t)SD * 2);
    u16*   VTb  = (u16*)take((size_t)SD * 2);
    float* scb  = (float*)take((size_t)SS * 4);
    u16*   Otmp = (u16*)take((size_t)N_X * 2);

    for (int b = 0; b < Bb; ++b) {
      const u16* xb = xn + (long)b * SD;
      dim3 gq(D / BN, S / BM, 1);  // (8, 16)
      gemm_nt<0><<<gq, 256, 0, stream>>>(xb, WqT, Qb,  D, D, D, D, 0, 0, 0, 1.f, 0, 0);
      gemm_nt<0><<<gq, 256, 0, stream>>>(xb, WkT, Kbb, D, D, D, D, 0, 0, 0, 1.f, 0, 0);
      gemm_nt<0><<<gq, 256, 0, stream>>>(xb, WvT, Vb,  D, D, D, D, 0, 0, 0, 1.f, 0, 0);

      transpose_bf16<<<dim3(D / 64, S / 64, 1), 256, 0, stream>>>(Vb, VTb, S, D, 0, 0);

      gemm_nt<1><<<dim3(S / BN, S / BM, 1), 256, 0, stream>>>(Qb, Kbb, scb, D, D, D, S,
                                                              0, 0, 0, scl, 1, 0);
      softmax_causal<<<S, 256, 0, stream>>>((char*)scb, (long)S * 4, S, S);
      gemm_nt<0><<<dim3(D / BN, S / BM, 1), 256, 0, stream>>>((u16*)scb, VTb,
                                                              Otmp + (long)b * SD,
                                                              S, 2 * S, S, D,
                                                              0, 0, 0, 1.f, 0, 1);
    }
    writeout<<<(int)(N_X / 256), 256, 0, stream>>>(Otmp, d_out, flag);
  }
}

// Round 3
// 312.332 us; speedup vs baseline: 3.8065x; 3.8065x over previous
//
#include <hip/hip_runtime.h>
#include <stdint.h>

typedef unsigned short u16;
typedef unsigned int u32;
typedef __bf16 bf16x8 __attribute__((ext_vector_type(8)));
typedef float f32x4 __attribute__((ext_vector_type(4)));

#define BM 128
#define BN 128
#define BK 64

__device__ __forceinline__ u16 f2bf(float x) {
  union { float f; uint32_t u; } c; c.f = x;
  uint32_t r = (c.u + 0x7FFFu + ((c.u >> 16) & 1u)) >> 16;
  return (u16)r;
}
__device__ __forceinline__ float bf2f(u16 v) {
  union { uint32_t u; float f; } c; c.u = ((uint32_t)v) << 16;
  return c.f;
}

// async global->LDS, 16B per lane; LDS dest = wave-uniform base + lane*16
__device__ __forceinline__ void async_copy16(const u16* g, u16* l) {
  __builtin_amdgcn_global_load_lds(
      (const __attribute__((address_space(1))) void*)g,
      (__attribute__((address_space(3))) void*)l,
      16, 0, 0);
}

// ---------- dtype detection (parallel): count exp==0xFF bit patterns -------
// bf16 weights (|w|~0.03) never set all exponent bits; f32 mantissa halves
// hit the pattern ~1/256. Count > 32 over 256K samples => inputs are f32.
__global__ void flag_init(u32* __restrict__ f) { if (threadIdx.x == 0) *f = 0; }

__global__ void detect_dtype(const u16* __restrict__ w, u32* __restrict__ cnt) {
  int i = blockIdx.x * 256 + threadIdx.x;
  if ((w[i] & 0x7F80u) == 0x7F80u) atomicAdd(cnt, 1u);
}

// normalize input tensor to bf16 (copy if already bf16, convert if f32)
__global__ void normalize_in(const void* __restrict__ src, u16* __restrict__ dst,
                             const u32* __restrict__ flag) {
  long i = (long)blockIdx.x * 256 + threadIdx.x;
  if (*flag > 32) dst[i] = f2bf(((const float*)src)[i]);
  else            dst[i] = ((const u16*)src)[i];
}

__global__ void zerofill_u16(u16* __restrict__ p) {
  long i = (long)blockIdx.x * 256 + threadIdx.x;
  p[i] = 0;
}

// ---------- NT GEMM: A [M,K] bf16, B [N,K] bf16, C [M,N] ------------------
// MODE 0: bf16 out. MODE 1: f32 out. MODE 2: flag-selected bf16/f32 out.
// All apply scale. causal: skip 128-tiles strictly above diagonal.
// trik: limit K-loop to k < m0+BM (PV causal pruning).
template <int MODE>
__global__ __launch_bounds__(256, 2)
void gemm_nt(const u16* __restrict__ A, const u16* __restrict__ B, void* __restrict__ Cv,
             const u32* __restrict__ flag,
             int K, int lda, int ldb, int ldc,
             long sA, long sB, long sC, long cOff,
             float scale, int causal, int trik)
{
  const int bm = blockIdx.y, bn = blockIdx.x, bz = blockIdx.z;
  if (causal && bn > bm) return;

  __shared__ u16 As[BM * BK];
  __shared__ u16 Bs[BN * BK];

  A += (long)bz * sA;
  B += (long)bz * sB;

  const int tid  = threadIdx.x;
  const int wid  = tid >> 6;
  const int lane = tid & 63;
  const int l16  = lane & 15;
  const int lk   = lane >> 4;       // 0..3
  const int srow = lane >> 3;       // 0..7   (staging row within 8-row slab)
  const int scol = (lane & 7) * 8;  // staging col (elements)
  const int m0 = bm * BM, n0 = bn * BN;

  int nk = K / BK;
  if (trik) { int lim = (m0 + BM) / BK; if (lim < nk) nk = lim; }

  f32x4 acc[4][4] = {};

  for (int kt = 0; kt < nk; ++kt) {
    const int k0 = kt * BK;
#pragma unroll
    for (int c = 0; c < 4; ++c) {
      const int rb = wid * 32 + c * 8;  // wave-uniform 8-row slab base
      async_copy16(A + (long)(m0 + rb + srow) * lda + (k0 + scol), As + rb * BK);
      async_copy16(B + (long)(n0 + rb + srow) * ldb + (k0 + scol), Bs + rb * BK);
    }
    __syncthreads();
#pragma unroll
    for (int kh = 0; kh < 2; ++kh) {
      bf16x8 av[4], bv[4];
#pragma unroll
      for (int i = 0; i < 4; ++i) {
        av[i] = *(const bf16x8*)(As + ((wid >> 1) * 64 + i * 16 + l16) * BK + kh * 32 + lk * 8);
        bv[i] = *(const bf16x8*)(Bs + ((wid & 1) * 64 + i * 16 + l16) * BK + kh * 32 + lk * 8);
      }
#pragma unroll
      for (int mi = 0; mi < 4; ++mi)
#pragma unroll
        for (int ni = 0; ni < 4; ++ni)
          acc[mi][ni] = __builtin_amdgcn_mfma_f32_16x16x32_bf16(av[mi], bv[ni], acc[mi][ni], 0, 0, 0);
    }
    __syncthreads();
  }

  // C/D layout (m89-verified): col = lane&15, row = (lane>>4)*4 + reg
  const int rb0 = m0 + (wid >> 1) * 64;
  const int cb0 = n0 + (wid & 1) * 64;
  const long cbase = (long)bz * sC + cOff;
  const bool f32out = (MODE == 1) || (MODE == 2 && *flag > 32);

#pragma unroll
  for (int mi = 0; mi < 4; ++mi)
#pragma unroll
    for (int ni = 0; ni < 4; ++ni) {
      const int row = rb0 + mi * 16 + lk * 4;
      const int col = cb0 + ni * 16 + l16;
#pragma unroll
      for (int r = 0; r < 4; ++r) {
        const float v = acc[mi][ni][r] * scale;
        const long idx = cbase + (long)(row + r) * ldc + col;
        if constexpr (MODE == 0) {
          ((u16*)Cv)[idx] = f2bf(v);
        } else if constexpr (MODE == 1) {
          ((float*)Cv)[idx] = v;
        } else {
          if (f32out) ((float*)Cv)[idx] = v;
          else        ((u16*)Cv)[idx]   = f2bf(v);
        }
      }
    }
}

// ---------- bf16 tile transpose: out[c][r] = in[r][c], 64x64 LDS tiles -----
__global__ __launch_bounds__(256)
void transpose_bf16(const u16* __restrict__ in, u16* __restrict__ out,
                    int ldIn, int ldOut, long sIn, long sOut)
{
  __shared__ u16 tile[64][72];
  const int bz = blockIdx.z;
  in  += (long)bz * sIn;
  out += (long)bz * sOut;
  const int r0 = blockIdx.y * 64, c0 = blockIdx.x * 64;
  const int tid = threadIdx.x;
#pragma unroll
  for (int p = 0; p < 2; ++p) {
    int v = tid + p * 256;
    int row = v >> 3, c8 = (v & 7) * 8;
    union { uint4 q; u16 s[8]; } t;
    t.q = *(const uint4*)(in + (long)(r0 + row) * ldIn + c0 + c8);
#pragma unroll
    for (int i = 0; i < 8; ++i) tile[row][c8 + i] = t.s[i];
  }
  __syncthreads();
#pragma unroll
  for (int p = 0; p < 2; ++p) {
    int v = tid + p * 256;
    int oc = v >> 3, r8 = (v & 7) * 8;
    union { uint4 q; u16 s[8]; } t;
#pragma unroll
    for (int i = 0; i < 8; ++i) t.s[i] = tile[r8 + i][oc];
    *(uint4*)(out + (long)(c0 + oc) * ldOut + r0 + r8) = t.q;
  }
}

// ---------- causal softmax, f32 scores in, bf16 probs IN-PLACE at row head -
// score row cached in registers on the max pass (single global read).
__global__ __launch_bounds__(256)
void softmax_causal(char* __restrict__ base, long rowStrideB, int S, int modS)
{
  const long r = blockIdx.x;
  const int i = (int)(r % modS);
  float* sc = (float*)(base + r * rowStrideB);
  u16*   pr = (u16*)(base + r * rowStrideB);
  const int n = i + 1;
  const int tid = threadIdx.x;
  const int wv = tid >> 6, lane = tid & 63;
  __shared__ float red[4];

  float e[8];
  int cnt = 0;
  float m = -3.0e38f;
  for (int j = tid; j < n; j += 256) { float x = sc[j]; e[cnt++] = x; m = fmaxf(m, x); }
#pragma unroll
  for (int o = 32; o > 0; o >>= 1) m = fmaxf(m, __shfl_xor(m, o));
  if (lane == 0) red[wv] = m;
  __syncthreads();
  m = fmaxf(fmaxf(red[0], red[1]), fmaxf(red[2], red[3]));
  __syncthreads();

  float s = 0.f;
#pragma unroll
  for (int c = 0; c < 8; ++c)
    if (c < cnt) { float x = __expf(e[c] - m); e[c] = x; s += x; }
#pragma unroll
  for (int o = 32; o > 0; o >>= 1) s += __shfl_xor(s, o);
  if (lane == 0) red[wv] = s;
  __syncthreads();                      // all f32 reads of this row done
  s = red[0] + red[1] + red[2] + red[3];
  const float inv = 1.0f / s;

  cnt = 0;
  for (int j = tid; j < S; j += 256) {
    u16 v = 0;
    if (j < n) v = f2bf(e[cnt++] * inv);
    pr[j] = v;                          // overwrites first half of f32 row
  }
}

extern "C" void kernel_launch(void* const* d_in, const int* in_sizes, int n_in,
                              void* d_out, int out_size, void* d_ws, size_t ws_size,
                              hipStream_t stream)
{
  (void)in_sizes; (void)n_in; (void)out_size;
  const int Bb = 4, S = 2048, D = 1024, D3 = 3072;
  const long SD = (long)S * D;            // 2,097,152
  const long SS = (long)S * S;            // 4,194,304
  const long N_X = (long)Bb * SD;         // 8,388,608
  const long N_W = (long)D * D;           // 1,048,576

  char* ws = (char*)d_ws;
  size_t off = 0;
  auto take = [&](size_t bytes) -> void* {
    void* p = ws + off;
    off = (off + bytes + 255) & ~((size_t)255);
    return p;
  };

  // ---- common allocations (~28 MB)
  u32* flag = (u32*)take(4096);
  u16* xn   = (u16*)take((size_t)N_X * 2);
  u16* wn3  = (u16*)take((size_t)3 * N_W * 2);   // packed Wq|Wk|Wv (bf16)
  u16* WT3  = (u16*)take((size_t)3 * N_W * 2);   // packed Wq^T|Wk^T|Wv^T
  const size_t off_common = off;

  const size_t needA = off_common + (size_t)(N_X * 3 * 2)      // QKV packed 48 MB
                     + (size_t)(N_X * 2)                       // VT 16 MB
                     + (size_t)(Bb * SS * 4) + 4096;           // scores 64 MB
  const size_t needC = off_common + (size_t)(S * (long)D3 * 2) // QKVb 12 MB
                     + (size_t)(SD * 2)                        // VTb 4 MB
                     + (size_t)(SS * 4) + 4096;                // scb 16 MB

  if (ws_size < needC) {
    zerofill_u16<<<(int)(N_X / 256), 256, 0, stream>>>((u16*)d_out);
    return;
  }

  // ---- parallel dtype detect (256K samples of Wq) ----
  flag_init<<<1, 64, 0, stream>>>(flag);
  detect_dtype<<<1024, 256, 0, stream>>>((const u16*)d_in[1], flag);

  // ---- normalize to bf16 ----
  normalize_in<<<(int)(N_X / 256), 256, 0, stream>>>(d_in[0], xn, flag);
  normalize_in<<<(int)(N_W / 256), 256, 0, stream>>>(d_in[1], wn3, flag);
  normalize_in<<<(int)(N_W / 256), 256, 0, stream>>>(d_in[2], wn3 + N_W, flag);
  normalize_in<<<(int)(N_W / 256), 256, 0, stream>>>(d_in[3], wn3 + 2 * N_W, flag);

  // ---- all three W -> W^T in one launch (packed [3][D][D]) ----
  transpose_bf16<<<dim3(D / 64, D / 64, 3), 256, 0, stream>>>(wn3, WT3, D, D, N_W, N_W);

  const float scl = 0.03125f;  // 1024^-0.5

  if (ws_size >= needA) {
    // ================= Tier A: fully batched (~156 MB) =================
    u16*   QKV = (u16*)take((size_t)N_X * 3 * 2);   // [B*S][3072] = Q|K|V
    u16*   VT  = (u16*)take((size_t)N_X * 2);       // [B][D][S]
    float* sc  = (float*)take((size_t)Bb * SS * 4);

    // fused QKV projection: [8192,1024] @ [3072,1024]^T -> [8192,3072]
    gemm_nt<0><<<dim3(D3 / BN, (int)(N_X / D) / BM, 1), 256, 0, stream>>>(
        xn, WT3, QKV, flag, D, D, D, D3, 0, 0, 0, 0, 1.f, 0, 0);

    // V (cols 2048..3071 of QKV) -> VT per batch
    transpose_bf16<<<dim3(D / 64, S / 64, Bb), 256, 0, stream>>>(
        QKV + 2048, VT, D3, S, (long)S * D3, SD);

    // scores = (Q K^T) * scl, f32, lower-triangle tiles only
    gemm_nt<1><<<dim3(S / BN, S / BM, Bb), 256, 0, stream>>>(
        QKV, QKV + 1024, sc, flag, D, D3, D3, S,
        (long)S * D3, (long)S * D3, SS, 0, scl, 1, 0);

    softmax_causal<<<Bb * S, 256, 0, stream>>>((char*)sc, (long)S * 4, S, S);

    // out = P @ V (NT vs VT), causal K pruning, dtype-adaptive writeout
    gemm_nt<2><<<dim3(D / BN, S / BM, Bb), 256, 0, stream>>>(
        (u16*)sc, VT, d_out, flag, S, 2 * S, S, D,
        2 * SS, SD, SD, 0, 1.f, 0, 1);
  } else {
    // ================= Tier C: per-batch (~60 MB) =================
    u16*   QKVb = (u16*)take((size_t)S * D3 * 2);
    u16*   VTb  = (u16*)take((size_t)SD * 2);
    float* scb  = (float*)take((size_t)SS * 4);

    for (int b = 0; b < Bb; ++b) {
      gemm_nt<0><<<dim3(D3 / BN, S / BM, 1), 256, 0, stream>>>(
          xn + (long)b * SD, WT3, QKVb, flag, D, D, D, D3, 0, 0, 0, 0, 1.f, 0, 0);

      transpose_bf16<<<dim3(D / 64, S / 64, 1), 256, 0, stream>>>(
          QKVb + 2048, VTb, D3, S, 0, 0);

      gemm_nt<1><<<dim3(S / BN, S / BM, 1), 256, 0, stream>>>(
          QKVb, QKVb + 1024, scb, flag, D, D3, D3, S, 0, 0, 0, 0, scl, 1, 0);

      softmax_causal<<<S, 256, 0, stream>>>((char*)scb, (long)S * 4, S, S);

      gemm_nt<2><<<dim3(D / BN, S / BM, 1), 256, 0, stream>>>(
          (u16*)scb, VTb, d_out, flag, S, 2 * S, S, D,
          0, 0, 0, (long)b * SD, 1.f, 0, 1);
    }
  }
}

// Round 4
// 270.070 us; speedup vs baseline: 4.4021x; 1.1565x over previous
//
#include <hip/hip_runtime.h>
#include <stdint.h>

typedef unsigned short u16;
typedef unsigned int u32;
typedef __bf16 bf16x8 __attribute__((ext_vector_type(8)));
typedef float f32x4 __attribute__((ext_vector_type(4)));

#define BM 128
#define BN 128
#define BK 64

__device__ __forceinline__ u16 f2bf(float x) {
  union { float f; uint32_t u; } c; c.f = x;
  uint32_t r = (c.u + 0x7FFFu + ((c.u >> 16) & 1u)) >> 16;
  return (u16)r;
}

// async global->LDS, 16B per lane; LDS dest = wave-uniform base + lane*16
__device__ __forceinline__ void async_copy16(const u16* g, u16* l) {
  __builtin_amdgcn_global_load_lds(
      (const __attribute__((address_space(1))) void*)g,
      (__attribute__((address_space(3))) void*)l,
      16, 0, 0);
}

// ---------- dtype detection (parallel): count exp==0xFF bit patterns -------
__global__ void flag_init(u32* __restrict__ f) { if (threadIdx.x == 0) *f = 0; }

__global__ void detect_dtype(const u16* __restrict__ w, u32* __restrict__ cnt) {
  int i = blockIdx.x * 256 + threadIdx.x;
  if ((w[i] & 0x7F80u) == 0x7F80u) atomicAdd(cnt, 1u);
}

// normalize all four inputs to bf16 into one contiguous dst (xn | wq | wk | wv)
__global__ void normalize_all(const void* __restrict__ s0, const void* __restrict__ s1,
                              const void* __restrict__ s2, const void* __restrict__ s3,
                              u16* __restrict__ dst, const u32* __restrict__ flag,
                              long n0, long n1) {
  long i = (long)blockIdx.x * 256 + threadIdx.x;
  const void* src;
  long j;
  if (i < n0) { src = s0; j = i; }
  else {
    long t = i - n0;
    long w = t / n1;       // n1 is a power of two -> shift
    j = t - w * n1;
    src = (w == 0) ? s1 : (w == 1) ? s2 : s3;
  }
  if (*flag > 32) dst[i] = f2bf(((const float*)src)[j]);
  else            dst[i] = ((const u16*)src)[j];
}

__global__ void zerofill_u16(u16* __restrict__ p) {
  long i = (long)blockIdx.x * 256 + threadIdx.x;
  p[i] = 0;
}

// ---------- NT GEMM: A [M,K] bf16, B [N,K] bf16, C [M,N] ------------------
// LDS layout is XOR-swizzled on the GLOBAL-read side (slot [r][p] holds
// global 16B-chunk p^(r&7) of row r) so fragment ds_read_b128 is
// bank-conflict-free while global_load_lds keeps its base+lane*16 dest rule.
// MODE 0: bf16 out. MODE 1: f32 out. MODE 2: flag-selected bf16/f32 out.
template <int MODE>
__global__ __launch_bounds__(256, 2)
void gemm_nt(const u16* __restrict__ A, const u16* __restrict__ B, void* __restrict__ Cv,
             const u32* __restrict__ flag,
             int K, int lda, int ldb, int ldc,
             long sA, long sB, long sC, long cOff,
             float scale, int causal, int trik)
{
  const int bm = blockIdx.y, bn = blockIdx.x, bz = blockIdx.z;
  if (causal && bn > bm) return;

  __shared__ u16 As[BM * BK];
  __shared__ u16 Bs[BN * BK];

  A += (long)bz * sA;
  B += (long)bz * sB;

  const int tid  = threadIdx.x;
  const int wid  = tid >> 6;
  const int lane = tid & 63;
  const int l16  = lane & 15;
  const int lk   = lane >> 4;                   // 0..3
  const int srow = lane >> 3;                   // 0..7 (staging row in slab)
  const int swz  = ((lane & 7) ^ srow) * 8;     // swizzled staging col (elems)
  const int m0 = bm * BM, n0 = bn * BN;

  int nk = K / BK;
  if (trik) { int lim = (m0 + BM) / BK; if (lim < nk) nk = lim; }

  f32x4 acc[4][4] = {};

  for (int kt = 0; kt < nk; ++kt) {
    const int k0 = kt * BK;
#pragma unroll
    for (int c = 0; c < 4; ++c) {
      const int rb = wid * 32 + c * 8;          // wave-uniform 8-row slab base
      async_copy16(A + (long)(m0 + rb + srow) * lda + (k0 + swz), As + rb * BK);
      async_copy16(B + (long)(n0 + rb + srow) * ldb + (k0 + swz), Bs + rb * BK);
    }
    __syncthreads();
#pragma unroll
    for (int kh = 0; kh < 2; ++kh) {
      bf16x8 av[4], bv[4];
#pragma unroll
      for (int i = 0; i < 4; ++i) {
        const int Ra = (wid >> 1) * 64 + i * 16 + l16;
        const int Rb = (wid & 1)  * 64 + i * 16 + l16;
        const int ca = ((kh * 4 + lk) ^ (l16 & 7)) * 8;  // de-swizzled chunk
        av[i] = *(const bf16x8*)(As + Ra * BK + ca);
        bv[i] = *(const bf16x8*)(Bs + Rb * BK + ca);
      }
#pragma unroll
      for (int mi = 0; mi < 4; ++mi)
#pragma unroll
        for (int ni = 0; ni < 4; ++ni)
          acc[mi][ni] = __builtin_amdgcn_mfma_f32_16x16x32_bf16(av[mi], bv[ni], acc[mi][ni], 0, 0, 0);
    }
    __syncthreads();
  }

  // C/D layout (m89-verified): col = lane&15, row = (lane>>4)*4 + reg
  const int rb0 = m0 + (wid >> 1) * 64;
  const int cb0 = n0 + (wid & 1) * 64;
  const long cbase = (long)bz * sC + cOff;
  const bool f32out = (MODE == 1) || (MODE == 2 && *flag > 32);

#pragma unroll
  for (int mi = 0; mi < 4; ++mi)
#pragma unroll
    for (int ni = 0; ni < 4; ++ni) {
      const int row = rb0 + mi * 16 + lk * 4;
      const int col = cb0 + ni * 16 + l16;
#pragma unroll
      for (int r = 0; r < 4; ++r) {
        const float v = acc[mi][ni][r] * scale;
        const long idx = cbase + (long)(row + r) * ldc + col;
        if constexpr (MODE == 0) {
          ((u16*)Cv)[idx] = f2bf(v);
        } else if constexpr (MODE == 1) {
          ((float*)Cv)[idx] = v;
        } else {
          if (f32out) ((float*)Cv)[idx] = v;
          else        ((u16*)Cv)[idx]   = f2bf(v);
        }
      }
    }
}

// ---------- bf16 tile transpose: out[c][r] = in[r][c], 64x64 LDS tiles -----
__global__ __launch_bounds__(256)
void transpose_bf16(const u16* __restrict__ in, u16* __restrict__ out,
                    int ldIn, int ldOut, long sIn, long sOut)
{
  __shared__ u16 tile[64][72];
  const int bz = blockIdx.z;
  in  += (long)bz * sIn;
  out += (long)bz * sOut;
  const int r0 = blockIdx.y * 64, c0 = blockIdx.x * 64;
  const int tid = threadIdx.x;
#pragma unroll
  for (int p = 0; p < 2; ++p) {
    int v = tid + p * 256;
    int row = v >> 3, c8 = (v & 7) * 8;
    union { uint4 q; u16 s[8]; } t;
    t.q = *(const uint4*)(in + (long)(r0 + row) * ldIn + c0 + c8);
#pragma unroll
    for (int i = 0; i < 8; ++i) tile[row][c8 + i] = t.s[i];
  }
  __syncthreads();
#pragma unroll
  for (int p = 0; p < 2; ++p) {
    int v = tid + p * 256;
    int oc = v >> 3, r8 = (v & 7) * 8;
    union { uint4 q; u16 s[8]; } t;
#pragma unroll
    for (int i = 0; i < 8; ++i) t.s[i] = tile[r8 + i][oc];
    *(uint4*)(out + (long)(c0 + oc) * ldOut + r0 + r8) = t.q;
  }
}

// ---------- causal softmax, f32 scores in, bf16 probs IN-PLACE at row head -
__global__ __launch_bounds__(256)
void softmax_causal(char* __restrict__ base, long rowStrideB, int S, int modS)
{
  const long r = blockIdx.x;
  const int i = (int)(r % modS);
  float* sc = (float*)(base + r * rowStrideB);
  u16*   pr = (u16*)(base + r * rowStrideB);
  const int n = i + 1;
  const int tid = threadIdx.x;
  const int wv = tid >> 6, lane = tid & 63;
  __shared__ float red[4];

  float e[8];
  int cnt = 0;
  float m = -3.0e38f;
  for (int j = tid; j < n; j += 256) { float x = sc[j]; e[cnt++] = x; m = fmaxf(m, x); }
#pragma unroll
  for (int o = 32; o > 0; o >>= 1) m = fmaxf(m, __shfl_xor(m, o));
  if (lane == 0) red[wv] = m;
  __syncthreads();
  m = fmaxf(fmaxf(red[0], red[1]), fmaxf(red[2], red[3]));
  __syncthreads();

  float s = 0.f;
#pragma unroll
  for (int c = 0; c < 8; ++c)
    if (c < cnt) { float x = __expf(e[c] - m); e[c] = x; s += x; }
#pragma unroll
  for (int o = 32; o > 0; o >>= 1) s += __shfl_xor(s, o);
  if (lane == 0) red[wv] = s;
  __syncthreads();                      // all f32 reads of this row done
  s = red[0] + red[1] + red[2] + red[3];
  const float inv = 1.0f / s;

  cnt = 0;
  for (int j = tid; j < S; j += 256) {
    u16 v = 0;
    if (j < n) v = f2bf(e[cnt++] * inv);
    pr[j] = v;                          // overwrites first half of f32 row
  }
}

extern "C" void kernel_launch(void* const* d_in, const int* in_sizes, int n_in,
                              void* d_out, int out_size, void* d_ws, size_t ws_size,
                              hipStream_t stream)
{
  (void)in_sizes; (void)n_in; (void)out_size;
  const int Bb = 4, S = 2048, D = 1024, D3 = 3072;
  const long SD = (long)S * D;            // 2,097,152
  const long SS = (long)S * S;            // 4,194,304
  const long N_X = (long)Bb * SD;         // 8,388,608
  const long N_W = (long)D * D;           // 1,048,576

  char* ws = (char*)d_ws;
  size_t off = 0;
  auto take = [&](size_t bytes) -> void* {
    void* p = ws + off;
    off = (off + bytes + 255) & ~((size_t)255);
    return p;
  };

  // ---- common allocations (~28 MB). xn and wn3 are contiguous by layout.
  u32* flag = (u32*)take(4096);
  u16* xn   = (u16*)take((size_t)N_X * 2);
  u16* wn3  = (u16*)take((size_t)3 * N_W * 2);   // packed Wq|Wk|Wv (bf16)
  u16* WT3  = (u16*)take((size_t)3 * N_W * 2);   // packed Wq^T|Wk^T|Wv^T
  const size_t off_common = off;

  const size_t needA = off_common + (size_t)(N_X * 3 * 2)      // QKV packed 48 MB
                     + (size_t)(N_X * 2)                       // VT 16 MB
                     + (size_t)(Bb * SS * 4) + 4096;           // scores 64 MB
  const size_t needC = off_common + (size_t)(S * (long)D3 * 2) // QKVb 12 MB
                     + (size_t)(SD * 2)                        // VTb 4 MB
                     + (size_t)(SS * 4) + 4096;                // scb 16 MB

  if (ws_size < needC) {
    zerofill_u16<<<(int)(N_X / 256), 256, 0, stream>>>((u16*)d_out);
    return;
  }

  // ---- parallel dtype detect (256K samples of Wq) ----
  flag_init<<<1, 64, 0, stream>>>(flag);
  detect_dtype<<<1024, 256, 0, stream>>>((const u16*)d_in[1], flag);

  // ---- normalize all inputs to bf16 (single launch) ----
  normalize_all<<<(int)((N_X + 3 * N_W) / 256), 256, 0, stream>>>(
      d_in[0], d_in[1], d_in[2], d_in[3], xn, flag, N_X, N_W);

  // ---- all three W -> W^T in one launch (packed [3][D][D]) ----
  transpose_bf16<<<dim3(D / 64, D / 64, 3), 256, 0, stream>>>(wn3, WT3, D, D, N_W, N_W);

  const float scl = 0.03125f;  // 1024^-0.5

  if (ws_size >= needA) {
    // ================= Tier A: fully batched (~156 MB) =================
    u16*   QKV = (u16*)take((size_t)N_X * 3 * 2);   // [B*S][3072] = Q|K|V
    u16*   VT  = (u16*)take((size_t)N_X * 2);       // [B][D][S]
    float* sc  = (float*)take((size_t)Bb * SS * 4);

    // fused QKV projection: [8192,1024] @ [3072,1024]^T -> [8192,3072]
    gemm_nt<0><<<dim3(D3 / BN, (int)(N_X / D) / BM, 1), 256, 0, stream>>>(
        xn, WT3, QKV, flag, D, D, D, D3, 0, 0, 0, 0, 1.f, 0, 0);

    // V (cols 2048..3071 of QKV) -> VT per batch
    transpose_bf16<<<dim3(D / 64, S / 64, Bb), 256, 0, stream>>>(
        QKV + 2048, VT, D3, S, (long)S * D3, SD);

    // scores = (Q K^T) * scl, f32, lower-triangle tiles only
    gemm_nt<1><<<dim3(S / BN, S / BM, Bb), 256, 0, stream>>>(
        QKV, QKV + 1024, sc, flag, D, D3, D3, S,
        (long)S * D3, (long)S * D3, SS, 0, scl, 1, 0);

    softmax_causal<<<Bb * S, 256, 0, stream>>>((char*)sc, (long)S * 4, S, S);

    // out = P @ V (NT vs VT), causal K pruning, dtype-adaptive writeout
    gemm_nt<2><<<dim3(D / BN, S / BM, Bb), 256, 0, stream>>>(
        (u16*)sc, VT, d_out, flag, S, 2 * S, S, D,
        2 * SS, SD, SD, 0, 1.f, 0, 1);
  } else {
    // ================= Tier C: per-batch (~60 MB) =================
    u16*   QKVb = (u16*)take((size_t)S * D3 * 2);
    u16*   VTb  = (u16*)take((size_t)SD * 2);
    float* scb  = (float*)take((size_t)SS * 4);

    for (int b = 0; b < Bb; ++b) {
      gemm_nt<0><<<dim3(D3 / BN, S / BM, 1), 256, 0, stream>>>(
          xn + (long)b * SD, WT3, QKVb, flag, D, D, D, D3, 0, 0, 0, 0, 1.f, 0, 0);

      transpose_bf16<<<dim3(D / 64, S / 64, 1), 256, 0, stream>>>(
          QKVb + 2048, VTb, D3, S, 0, 0);

      gemm_nt<1><<<dim3(S / BN, S / BM, 1), 256, 0, stream>>>(
          QKVb, QKVb + 1024, scb, flag, D, D3, D3, S, 0, 0, 0, 0, scl, 1, 0);

      softmax_causal<<<S, 256, 0, stream>>>((char*)scb, (long)S * 4, S, S);

      gemm_nt<2><<<dim3(D / BN, S / BM, 1), 256, 0, stream>>>(
          (u16*)scb, VTb, d_out, flag, S, 2 * S, S, D,
          0, 0, 0, (long)b * SD, 1.f, 0, 1);
    }
  }
}

// Round 5
// 255.435 us; speedup vs baseline: 4.6543x; 1.0573x over previous
//
#include <hip/hip_runtime.h>
#include <stdint.h>

typedef unsigned short u16;
typedef unsigned int u32;
typedef __bf16 bf16x8 __attribute__((ext_vector_type(8)));
typedef float f32x4 __attribute__((ext_vector_type(4)));

#define BM 128
#define BN 128
#define BK 64

__device__ __forceinline__ u16 f2bf(float x) {
  union { float f; uint32_t u; } c; c.f = x;
  uint32_t r = (c.u + 0x7FFFu + ((c.u >> 16) & 1u)) >> 16;
  return (u16)r;
}

// async global->LDS, 16B per lane; LDS dest = wave-uniform base + lane*16
__device__ __forceinline__ void async_copy16(const u16* g, u16* l) {
  __builtin_amdgcn_global_load_lds(
      (const __attribute__((address_space(1))) void*)g,
      (__attribute__((address_space(3))) void*)l,
      16, 0, 0);
}

// ---------- dtype detection (parallel): count exp==0xFF bit patterns -------
__global__ void flag_init(u32* __restrict__ f) { if (threadIdx.x == 0) *f = 0; }

__global__ void detect_dtype(const u16* __restrict__ w, u32* __restrict__ cnt) {
  int i = blockIdx.x * 256 + threadIdx.x;
  if ((w[i] & 0x7F80u) == 0x7F80u) atomicAdd(cnt, 1u);
}

// normalize x to bf16, 8 elems/thread, vectorized both paths
__global__ __launch_bounds__(256)
void normalize_x(const void* __restrict__ src, u16* __restrict__ dst,
                 const u32* __restrict__ flag, long n) {
  long i = ((long)blockIdx.x * 256 + threadIdx.x) * 8;
  if (i >= n) return;
  u16 o[8];
  if (*flag > 32) {
    const float* s = (const float*)src + i;
    f32x4 a = *(const f32x4*)s;
    f32x4 b = *(const f32x4*)(s + 4);
#pragma unroll
    for (int c = 0; c < 4; ++c) { o[c] = f2bf(a[c]); o[c + 4] = f2bf(b[c]); }
  } else {
    *(uint4*)o = *(const uint4*)((const u16*)src + i);
  }
  *(uint4*)(dst + i) = *(uint4*)o;
}

__global__ void zerofill_u16(u16* __restrict__ p) {
  long i = (long)blockIdx.x * 256 + threadIdx.x;
  p[i] = 0;
}

// ---------- fused normalize + transpose for the three weights --------------
// reads W[z] (f32 or bf16 per flag) [D][D], writes bf16 W^T into dst[z]
__global__ __launch_bounds__(256)
void transnorm_w(const void* __restrict__ s0, const void* __restrict__ s1,
                 const void* __restrict__ s2, u16* __restrict__ dst,
                 const u32* __restrict__ flag, int Dd)
{
  __shared__ u16 tile[64][72];
  const int z = blockIdx.z;
  const void* src = (z == 0) ? s0 : (z == 1) ? s1 : s2;
  u16* out = dst + (long)z * Dd * Dd;
  const int r0 = blockIdx.y * 64, c0 = blockIdx.x * 64;
  const int tid = threadIdx.x;
  const bool isf32 = (*flag > 32);
#pragma unroll
  for (int p = 0; p < 2; ++p) {
    int v = tid + p * 256;
    int row = v >> 3, c8 = (v & 7) * 8;
    u16 t[8];
    if (isf32) {
      const float* sp = (const float*)src + (long)(r0 + row) * Dd + c0 + c8;
      f32x4 a = *(const f32x4*)sp;
      f32x4 b = *(const f32x4*)(sp + 4);
#pragma unroll
      for (int c = 0; c < 4; ++c) { t[c] = f2bf(a[c]); t[c + 4] = f2bf(b[c]); }
    } else {
      *(uint4*)t = *(const uint4*)((const u16*)src + (long)(r0 + row) * Dd + c0 + c8);
    }
#pragma unroll
    for (int c = 0; c < 8; ++c) tile[row][c8 + c] = t[c];
  }
  __syncthreads();
#pragma unroll
  for (int p = 0; p < 2; ++p) {
    int v = tid + p * 256;
    int oc = v >> 3, r8 = (v & 7) * 8;
    union { uint4 q; u16 s[8]; } t;
#pragma unroll
    for (int c = 0; c < 8; ++c) t.s[c] = tile[r8 + c][oc];
    *(uint4*)(out + (long)(c0 + oc) * Dd + r0 + r8) = t.q;
  }
}

// ---------- NT GEMM: A [M,K] bf16, B [N,K] bf16, C [M,N] ------------------
// LDS layout XOR-swizzled on the GLOBAL-read side: slot [r][p] holds global
// 16B-chunk p^(r&7) of row r -> ds_read_b128 is bank-conflict-free while
// global_load_lds keeps its base+lane*16 dest rule (verified r4: conflicts=0).
// MODE 0: bf16 out. MODE 1: f32 out. MODE 2: flag-selected bf16/f32 out.
// trik: K-loop limited to k < m0+BM (PV causal pruning) + longest-first bm.
template <int MODE>
__global__ __launch_bounds__(256, 2)
void gemm_nt(const u16* __restrict__ A, const u16* __restrict__ B, void* __restrict__ Cv,
             const u32* __restrict__ flag,
             int K, int lda, int ldb, int ldc,
             long sA, long sB, long sC, long cOff,
             float scale, int causal, int trik)
{
  int bm = blockIdx.y;
  if (trik) bm = gridDim.y - 1 - bm;   // longest blocks dispatched first
  const int bn = blockIdx.x, bz = blockIdx.z;
  if (causal && bn > bm) return;

  __shared__ u16 As[BM * BK];
  __shared__ u16 Bs[BN * BK];

  A += (long)bz * sA;
  B += (long)bz * sB;

  const int tid  = threadIdx.x;
  const int wid  = tid >> 6;
  const int lane = tid & 63;
  const int l16  = lane & 15;
  const int lk   = lane >> 4;                   // 0..3
  const int srow = lane >> 3;                   // 0..7 (staging row in slab)
  const int swz  = ((lane & 7) ^ srow) * 8;     // swizzled staging col (elems)
  const int m0 = bm * BM, n0 = bn * BN;

  int nk = K / BK;
  if (trik) { int lim = (m0 + BM) / BK; if (lim < nk) nk = lim; }

  f32x4 acc[4][4] = {};

  for (int kt = 0; kt < nk; ++kt) {
    const int k0 = kt * BK;
#pragma unroll
    for (int c = 0; c < 4; ++c) {
      const int rb = wid * 32 + c * 8;          // wave-uniform 8-row slab base
      async_copy16(A + (long)(m0 + rb + srow) * lda + (k0 + swz), As + rb * BK);
      async_copy16(B + (long)(n0 + rb + srow) * ldb + (k0 + swz), Bs + rb * BK);
    }
    __syncthreads();
#pragma unroll
    for (int kh = 0; kh < 2; ++kh) {
      bf16x8 av[4], bv[4];
#pragma unroll
      for (int i = 0; i < 4; ++i) {
        const int Ra = (wid >> 1) * 64 + i * 16 + l16;
        const int Rb = (wid & 1)  * 64 + i * 16 + l16;
        const int ca = ((kh * 4 + lk) ^ (l16 & 7)) * 8;  // de-swizzled chunk
        av[i] = *(const bf16x8*)(As + Ra * BK + ca);
        bv[i] = *(const bf16x8*)(Bs + Rb * BK + ca);
      }
#pragma unroll
      for (int mi = 0; mi < 4; ++mi)
#pragma unroll
        for (int ni = 0; ni < 4; ++ni)
          acc[mi][ni] = __builtin_amdgcn_mfma_f32_16x16x32_bf16(av[mi], bv[ni], acc[mi][ni], 0, 0, 0);
    }
    __syncthreads();
  }

  // C/D layout (m89-verified): col = lane&15, row = (lane>>4)*4 + reg
  const int rb0 = m0 + (wid >> 1) * 64;
  const int cb0 = n0 + (wid & 1) * 64;
  const long cbase = (long)bz * sC + cOff;
  const bool f32out = (MODE == 1) || (MODE == 2 && *flag > 32);

#pragma unroll
  for (int mi = 0; mi < 4; ++mi)
#pragma unroll
    for (int ni = 0; ni < 4; ++ni) {
      const int row = rb0 + mi * 16 + lk * 4;
      const int col = cb0 + ni * 16 + l16;
#pragma unroll
      for (int r = 0; r < 4; ++r) {
        const float v = acc[mi][ni][r] * scale;
        const long idx = cbase + (long)(row + r) * ldc + col;
        if constexpr (MODE == 0) {
          ((u16*)Cv)[idx] = f2bf(v);
        } else if constexpr (MODE == 1) {
          ((float*)Cv)[idx] = v;
        } else {
          if (f32out) ((float*)Cv)[idx] = v;
          else        ((u16*)Cv)[idx]   = f2bf(v);
        }
      }
    }
}

// ---------- bf16 tile transpose: out[c][r] = in[r][c], 64x64 LDS tiles -----
__global__ __launch_bounds__(256)
void transpose_bf16(const u16* __restrict__ in, u16* __restrict__ out,
                    int ldIn, int ldOut, long sIn, long sOut)
{
  __shared__ u16 tile[64][72];
  const int bz = blockIdx.z;
  in  += (long)bz * sIn;
  out += (long)bz * sOut;
  const int r0 = blockIdx.y * 64, c0 = blockIdx.x * 64;
  const int tid = threadIdx.x;
#pragma unroll
  for (int p = 0; p < 2; ++p) {
    int v = tid + p * 256;
    int row = v >> 3, c8 = (v & 7) * 8;
    union { uint4 q; u16 s[8]; } t;
    t.q = *(const uint4*)(in + (long)(r0 + row) * ldIn + c0 + c8);
#pragma unroll
    for (int i = 0; i < 8; ++i) tile[row][c8 + i] = t.s[i];
  }
  __syncthreads();
#pragma unroll
  for (int p = 0; p < 2; ++p) {
    int v = tid + p * 256;
    int oc = v >> 3, r8 = (v & 7) * 8;
    union { uint4 q; u16 s[8]; } t;
#pragma unroll
    for (int i = 0; i < 8; ++i) t.s[i] = tile[r8 + i][oc];
    *(uint4*)(out + (long)(c0 + oc) * ldOut + r0 + r8) = t.q;
  }
}

// ---------- causal softmax, one pass: 256 thr x 8 elems = S ----------------
// f32 scores in, bf16 probs written IN-PLACE at the row head. Vector loads
// only where j<n (predicated whole-vector), packed uint4 stores. All f32
// reads complete before the first barrier; stores happen after the last.
__global__ __launch_bounds__(256)
void softmax_causal(char* __restrict__ base, long rowStrideB, int modS)
{
  const long r = blockIdx.x;
  const int i = (int)(r % modS);
  float* sc = (float*)(base + r * rowStrideB);
  u16*   pr = (u16*)(base + r * rowStrideB);
  const int n = i + 1;
  const int tid = threadIdx.x;
  const int j0 = tid * 8;
  const int wv = tid >> 6, lane = tid & 63;
  __shared__ float red[4];

  float e[8];
  float m = -3.0e38f;
  if (j0 < n) {
    f32x4 a = *(const f32x4*)(sc + j0);
    f32x4 b = *(const f32x4*)(sc + j0 + 4);
#pragma unroll
    for (int c = 0; c < 4; ++c) { e[c] = a[c]; e[c + 4] = b[c]; }
#pragma unroll
    for (int c = 0; c < 8; ++c) {
      if (j0 + c < n) m = fmaxf(m, e[c]); else e[c] = -3.0e38f;
    }
  } else {
#pragma unroll
    for (int c = 0; c < 8; ++c) e[c] = -3.0e38f;
  }
#pragma unroll
  for (int o = 32; o > 0; o >>= 1) m = fmaxf(m, __shfl_xor(m, o));
  if (lane == 0) red[wv] = m;
  __syncthreads();
  m = fmaxf(fmaxf(red[0], red[1]), fmaxf(red[2], red[3]));
  __syncthreads();

  float s = 0.f;
#pragma unroll
  for (int c = 0; c < 8; ++c) { float x = __expf(e[c] - m); e[c] = x; s += x; }
#pragma unroll
  for (int o = 32; o > 0; o >>= 1) s += __shfl_xor(s, o);
  if (lane == 0) red[wv] = s;
  __syncthreads();
  s = red[0] + red[1] + red[2] + red[3];
  const float inv = 1.0f / s;

  u16 o8[8];
#pragma unroll
  for (int c = 0; c < 8; ++c) o8[c] = f2bf(e[c] * inv);  // masked lanes: exp->0
  *(uint4*)(pr + j0) = *(uint4*)o8;
}

extern "C" void kernel_launch(void* const* d_in, const int* in_sizes, int n_in,
                              void* d_out, int out_size, void* d_ws, size_t ws_size,
                              hipStream_t stream)
{
  (void)in_sizes; (void)n_in; (void)out_size;
  const int Bb = 4, S = 2048, D = 1024, D3 = 3072;
  const long SD = (long)S * D;            // 2,097,152
  const long SS = (long)S * S;            // 4,194,304
  const long N_X = (long)Bb * SD;         // 8,388,608
  const long N_W = (long)D * D;           // 1,048,576

  char* ws = (char*)d_ws;
  size_t off = 0;
  auto take = [&](size_t bytes) -> void* {
    void* p = ws + off;
    off = (off + bytes + 255) & ~((size_t)255);
    return p;
  };

  // ---- common allocations (~22 MB)
  u32* flag = (u32*)take(4096);
  u16* xn   = (u16*)take((size_t)N_X * 2);
  u16* WT3  = (u16*)take((size_t)3 * N_W * 2);   // packed Wq^T|Wk^T|Wv^T
  const size_t off_common = off;

  const size_t needA = off_common + (size_t)(N_X * 3 * 2)      // QKV packed 48 MB
                     + (size_t)(N_X * 2)                       // VT 16 MB
                     + (size_t)(Bb * SS * 4) + 4096;           // scores 64 MB
  const size_t needC = off_common + (size_t)(S * (long)D3 * 2) // QKVb 12 MB
                     + (size_t)(SD * 2)                        // VTb 4 MB
                     + (size_t)(SS * 4) + 4096;                // scb 16 MB

  if (ws_size < needC) {
    zerofill_u16<<<(int)(N_X / 256), 256, 0, stream>>>((u16*)d_out);
    return;
  }

  // ---- parallel dtype detect (256K samples of Wq) ----
  flag_init<<<1, 64, 0, stream>>>(flag);
  detect_dtype<<<1024, 256, 0, stream>>>((const u16*)d_in[1], flag);

  // ---- normalize x (vectorized) + fused normalize+transpose for weights ----
  normalize_x<<<(int)(N_X / 2048), 256, 0, stream>>>(d_in[0], xn, flag, N_X);
  transnorm_w<<<dim3(D / 64, D / 64, 3), 256, 0, stream>>>(
      d_in[1], d_in[2], d_in[3], WT3, flag, D);

  const float scl = 0.03125f;  // 1024^-0.5

  if (ws_size >= needA) {
    // ================= Tier A: fully batched (~150 MB) =================
    u16*   QKV = (u16*)take((size_t)N_X * 3 * 2);   // [B*S][3072] = Q|K|V
    u16*   VT  = (u16*)take((size_t)N_X * 2);       // [B][D][S]
    float* sc  = (float*)take((size_t)Bb * SS * 4);

    // fused QKV projection: [8192,1024] @ [3072,1024]^T -> [8192,3072]
    gemm_nt<0><<<dim3(D3 / BN, (int)(N_X / D) / BM, 1), 256, 0, stream>>>(
        xn, WT3, QKV, flag, D, D, D, D3, 0, 0, 0, 0, 1.f, 0, 0);

    // V (cols 2048..3071 of QKV) -> VT per batch
    transpose_bf16<<<dim3(D / 64, S / 64, Bb), 256, 0, stream>>>(
        QKV + 2048, VT, D3, S, (long)S * D3, SD);

    // scores = (Q K^T) * scl, f32, lower-triangle tiles only
    gemm_nt<1><<<dim3(S / BN, S / BM, Bb), 256, 0, stream>>>(
        QKV, QKV + 1024, sc, flag, D, D3, D3, S,
        (long)S * D3, (long)S * D3, SS, 0, scl, 1, 0);

    softmax_causal<<<Bb * S, 256, 0, stream>>>((char*)sc, (long)S * 4, S);

    // out = P @ V (NT vs VT), causal K pruning, dtype-adaptive writeout
    gemm_nt<2><<<dim3(D / BN, S / BM, Bb), 256, 0, stream>>>(
        (u16*)sc, VT, d_out, flag, S, 2 * S, S, D,
        2 * SS, SD, SD, 0, 1.f, 0, 1);
  } else {
    // ================= Tier C: per-batch (~54 MB) =================
    u16*   QKVb = (u16*)take((size_t)S * D3 * 2);
    u16*   VTb  = (u16*)take((size_t)SD * 2);
    float* scb  = (float*)take((size_t)SS * 4);

    for (int b = 0; b < Bb; ++b) {
      gemm_nt<0><<<dim3(D3 / BN, S / BM, 1), 256, 0, stream>>>(
          xn + (long)b * SD, WT3, QKVb, flag, D, D, D, D3, 0, 0, 0, 0, 1.f, 0, 0);

      transpose_bf16<<<dim3(D / 64, S / 64, 1), 256, 0, stream>>>(
          QKVb + 2048, VTb, D3, S, 0, 0);

      gemm_nt<1><<<dim3(S / BN, S / BM, 1), 256, 0, stream>>>(
          QKVb, QKVb + 1024, scb, flag, D, D3, D3, S, 0, 0, 0, 0, scl, 1, 0);

      softmax_causal<<<S, 256, 0, stream>>>((char*)scb, (long)S * 4, S);

      gemm_nt<2><<<dim3(D / BN, S / BM, 1), 256, 0, stream>>>(
          (u16*)scb, VTb, d_out, flag, S, 2 * S, S, D,
          0, 0, 0, (long)b * SD, 1.f, 0, 1);
    }
  }
}